// Round 3
// baseline (1735.607 us; speedup 1.0000x reference)
//
#include <hip/hip_runtime.h>
#include <cmath>

// Problem constants
#define Bb 256
#define Ss 50
#define Cc 40
#define Dd 256
#define Vv 20000

typedef __bf16 bf16;
typedef __bf16 bf16x8 __attribute__((ext_vector_type(8)));
typedef float f32x4 __attribute__((ext_vector_type(4)));

#define GL2LDS(g, l) __builtin_amdgcn_global_load_lds( \
    (__attribute__((address_space(1))) void*)(g), \
    (__attribute__((address_space(3))) void*)(l), 16, 0, 0)

// ---------------- ws layout (BYTE offsets) ----------------
// gates fp32 (12800x1024)        @ 0          (52,428,800)
//   emb_bf16 (20001x256)         @ 0          (10,240,512)  [dead after embed]
//   -- after recurrence, region reused:
//   aligned fp32 (12800x256)     @ 0          (13,107,200)
//   cat bf16 (12544x512)         @ 13,107,200 (12,845,056)
//   tmp bf16 (12800x256)         @ 25,952,256 ( 6,553,600)
//   H1 fp32 (12544x64)           @ 32,505,856 ( 3,211,264)
//   attnw fp32 (12544x2)         @ 35,717,120 (   100,352)
// x fp32 (12800x256)             @ 52,428,800 (13,107,200)
// x bf16                         @ 65,536,000 ( 6,553,600)
// rnn bf16 (12800x256)           @ 72,089,600 ( 6,553,600)
// w fp32 (12800x256)             @ 78,643,200 (13,107,200)
// Wih bf16 (1024x256)            @ 92,012,544 (   524,288)
// Whh bf16 (1024x256)            @ 92,536,832 (   524,288)
// Whk bf16 (256x256)             @ 93,061,120 (   131,072)
// W1  bf16 (64x512)              @ 93,192,192 (    65,536)
// WdiffT bf16 (256x256)          @ 93,257,728 (   131,072)
// salpha fp32 (256)              @ 93,388,800
// sbeta  fp32 (256)              @ 93,389,824
// barrier cnt (16x64 int)        @ 93,390,848 (     4,096)  [memset 0 each call]
// total ~93.4 MB
#define OFFB_GATES    0ull
#define OFFB_EMBB     0ull
#define OFFB_ALIGNED  0ull
#define OFFB_CAT      13107200ull
#define OFFB_TMPB     25952256ull
#define OFFB_H1       32505856ull
#define OFFB_ATTNW    35717120ull
#define OFFB_X        52428800ull
#define OFFB_XB       65536000ull
#define OFFB_RNNB     72089600ull
#define OFFB_W        78643200ull
#define OFFB_WIHB     92012544ull
#define OFFB_WHHB     92536832ull
#define OFFB_WHKB     93061120ull
#define OFFB_W1B      93192192ull
#define OFFB_WDTB     93257728ull
#define OFFB_SALPHA   93388800ull
#define OFFB_SBETA    93389824ull
#define OFFB_BAR      93390848ull

// ---------------- bf16 MFMA GEMM (unchanged from R2) ----------------
template<int BM, int BN, int ACT>
__global__ __launch_bounds__(256) void mfma_gemm(
    const bf16* __restrict__ A, int lda,
    const bf16* __restrict__ B, int ldb,
    const float* __restrict__ bias1, const float* __restrict__ bias2,
    float* __restrict__ C, int ldc, int K)
{
    constexpr int BK = 32;
    constexpr int NF = BN / 32;
    __shared__ bf16 As[BM * BK];
    __shared__ bf16 Bs[BN * BK];
    const int tid  = threadIdx.x;
    const int wave = tid >> 6;
    const int lane = tid & 63;
    const int m0 = blockIdx.x * BM;
    const int n0 = blockIdx.y * BN;
    const int wm = (wave >> 1) * 64;
    const int wn = (wave & 1) * (BN / 2);

    f32x4 acc[4][NF];
#pragma unroll
    for (int i = 0; i < 4; ++i)
#pragma unroll
        for (int j = 0; j < NF; ++j) acc[i][j] = (f32x4){0.f, 0.f, 0.f, 0.f};

    const int ar = tid >> 2;
    const int ac = tid & 3;
    const int sw = ac ^ (ar & 3);
    const int lr = lane & 15;
    const int q  = lane >> 4;

    for (int k0 = 0; k0 < K; k0 += BK) {
        __syncthreads();
#pragma unroll
        for (int it = 0; it < BM / 64; ++it) {
            const bf16* gp = A + (size_t)(m0 + it * 64 + ar) * lda + k0 + sw * 8;
            GL2LDS(gp, As + it * 2048 + wave * 512);
        }
#pragma unroll
        for (int it = 0; it < BN / 64; ++it) {
            const bf16* gp = B + (size_t)(n0 + it * 64 + ar) * ldb + k0 + sw * 8;
            GL2LDS(gp, Bs + it * 2048 + wave * 512);
        }
        __syncthreads();

        bf16x8 af[4], bfv[NF];
#pragma unroll
        for (int fm = 0; fm < 4; ++fm) {
            int m = wm + fm * 16 + lr;
            af[fm] = *(const bf16x8*)(As + m * 32 + ((q ^ (m & 3)) * 8));
        }
#pragma unroll
        for (int fn = 0; fn < NF; ++fn) {
            int n = wn + fn * 16 + lr;
            bfv[fn] = *(const bf16x8*)(Bs + n * 32 + ((q ^ (n & 3)) * 8));
        }
#pragma unroll
        for (int fm = 0; fm < 4; ++fm)
#pragma unroll
            for (int fn = 0; fn < NF; ++fn)
                acc[fm][fn] = __builtin_amdgcn_mfma_f32_16x16x32_bf16(
                    af[fm], bfv[fn], acc[fm][fn], 0, 0, 0);
    }

    const int rbase = q * 4;
#pragma unroll
    for (int fn = 0; fn < NF; ++fn) {
        const int col = n0 + wn + fn * 16 + lr;
        float bb = 0.f;
        if (bias1) bb += bias1[col];
        if (bias2) bb += bias2[col];
#pragma unroll
        for (int fm = 0; fm < 4; ++fm) {
            f32x4 v = acc[fm][fn];
#pragma unroll
            for (int r = 0; r < 4; ++r) {
                const int row = m0 + wm + fm * 16 + rbase + r;
                float val = v[r] + bb;
                if (ACT == 1) val = tanhf(val);
                C[(size_t)row * ldc + col] = val;
            }
        }
    }
}

// ---------------- persistent LSTM recurrence (single launch) ----------------
// 256 blocks x 256 threads, all co-resident (grid == CU count). Block
// (bm = blk&15, bd = blk>>4): batches bm*16..+15, hidden cols bd*16..+15.
// Wave g holds gate g's Whh fragment slice in REGISTERS (loaded once).
// c lives in registers (thread (m,d) owns one value). Per step, the 16
// blocks sharing bm sync via a device-scope atomic counter: release =
// syncthreads (drain stores) + threadfence + atomicAdd; acquire = spin +
// threadfence. h addresses are step-unique; counters monotonic (no ABA).
__global__ __launch_bounds__(256) void lstm_persist(
    const bf16* __restrict__ Whhb,    // (1024 x 256) N x K
    const float* __restrict__ gates,  // (B*S x 1024) x@Wih^T+bih+bhh
    bf16* __restrict__ rnnb,          // (B*S x 256) h outputs
    int* __restrict__ barcnt)         // 16 counters, 256B apart, zeroed
{
    const int tid  = threadIdx.x;
    const int g    = tid >> 6;
    const int lane = tid & 63;
    const int bm   = blockIdx.x & 15;
    const int bd   = blockIdx.x >> 4;
    const int lr   = lane & 15;
    const int q    = lane >> 4;

    // Whh B-fragments, loaded once: row g*256+bd*16+lr, k = kc*32+q*8..+7
    bf16x8 breg[8];
    {
        const bf16* brow = Whhb + (size_t)(g * 256 + bd * 16 + lr) * Dd + q * 8;
#pragma unroll
        for (int kc = 0; kc < 8; ++kc) breg[kc] = *(const bf16x8*)(brow + kc * 32);
    }

    const int m  = tid >> 4, d = tid & 15;      // gate-math assignment
    const int b  = bm * 16 + m;
    const int gd = bd * 16 + d;
    float creg = 0.f;

    __shared__ float gc[4][16][16];
    int* cnt = barcnt + bm * 64;

    for (int t = 0; t < Ss; ++t) {
        // prefetch this thread's gate pre-activations (independent of h)
        const float* gp = gates + ((size_t)b * Ss + t) * 1024 + gd;
        float p0 = gp[0], p1 = gp[256], p2 = gp[512], p3 = gp[768];

        f32x4 acc = (f32x4){0.f, 0.f, 0.f, 0.f};
        if (t > 0) {
            if (tid == 0) {
                while (__hip_atomic_load(cnt, __ATOMIC_ACQUIRE,
                                         __HIP_MEMORY_SCOPE_AGENT) < 16 * t)
                    __builtin_amdgcn_s_sleep(2);
            }
            __syncthreads();
            __threadfence();  // acquire: invalidate stale cache before h reads
            const bf16* arow = rnnb + ((size_t)(bm * 16 + lr) * Ss + (t - 1)) * Dd + q * 8;
#pragma unroll
            for (int kc = 0; kc < 8; ++kc) {
                bf16x8 af = *(const bf16x8*)(arow + kc * 32);
                acc = __builtin_amdgcn_mfma_f32_16x16x32_bf16(af, breg[kc], acc, 0, 0, 0);
            }
        }
        // exchange gate tiles: gc[g][m][n]  (C/D: col=lane&15, row=q*4+reg)
        {
            const int rb = q * 4;
#pragma unroll
            for (int r = 0; r < 4; ++r) gc[g][rb + r][lr] = acc[r];
        }
        __syncthreads();

        float gi = gc[0][m][d] + p0;
        float gf = gc[1][m][d] + p1;
        float gg = gc[2][m][d] + p2;
        float go = gc[3][m][d] + p3;
        float ii = 1.f / (1.f + expf(-gi));
        float ff = 1.f / (1.f + expf(-gf));
        float g2 = tanhf(gg);
        float oo = 1.f / (1.f + expf(-go));
        creg = ff * creg + ii * g2;
        float h = oo * tanhf(creg);
        rnnb[((size_t)b * Ss + t) * Dd + gd] = (bf16)h;

        __syncthreads();      // drain all threads' h stores (vmcnt before barrier)
        if (tid == 0) {
            __threadfence();  // release: flush to device scope
            __hip_atomic_fetch_add(cnt, 1, __ATOMIC_RELEASE, __HIP_MEMORY_SCOPE_AGENT);
        }
        // gc reuse at t+1 is safe: next write happens after group-barrier wait
        // + syncthreads, which orders it after all reads above.
    }
}

// ---------------- weight converts (one launch) ----------------
// float4-granular segments: Wih[0,65536) Whh[65536,131072) Whk[131072,147456)
// W1[147456,155648). Grid 608 x 256.
__global__ __launch_bounds__(256) void cvt_weights_kernel(
    const float* __restrict__ Wih, const float* __restrict__ Whh,
    const float* __restrict__ Whk, const float* __restrict__ W1,
    bf16* __restrict__ Wihb, bf16* __restrict__ Whhb,
    bf16* __restrict__ Whkb, bf16* __restrict__ W1b)
{
    int i = blockIdx.x * 256 + threadIdx.x;   // float4 index
    const float* src; bf16* dst; int base;
    if (i < 65536)       { src = Wih; dst = Wihb; base = 0; }
    else if (i < 131072) { src = Whh; dst = Whhb; base = 65536; }
    else if (i < 147456) { src = Whk; dst = Whkb; base = 131072; }
    else                 { src = W1;  dst = W1b;  base = 147456; }
    int j = i - base;
    float4 v = *((const float4*)src + j);
    bf16* o = dst + j * 4;
    o[0] = (bf16)v.x; o[1] = (bf16)v.y; o[2] = (bf16)v.z; o[3] = (bf16)v.w;
}

// emb fp32 -> bf16 (float4 granular), n4 = 20001*256/4
__global__ __launch_bounds__(256) void cvt_emb_kernel(
    const float* __restrict__ src, bf16* __restrict__ dst, int n4)
{
    int i = blockIdx.x * 256 + threadIdx.x;
    if (i >= n4) return;
    float4 v = *((const float4*)src + i);
    bf16* o = dst + i * 4;
    o[0] = (bf16)v.x; o[1] = (bf16)v.y; o[2] = (bf16)v.z; o[3] = (bf16)v.w;
}

// transpose + convert: in (R x C) fp32 -> out (C x R) bf16
__global__ __launch_bounds__(256) void transpose_cvt_kernel(
    const float* __restrict__ in, bf16* __restrict__ out, int R, int C)
{
    __shared__ float t[32][33];
    const int c0 = blockIdx.x * 32, r0 = blockIdx.y * 32;
    const int tx = threadIdx.x & 31, ty = threadIdx.x >> 5;
    for (int i = ty; i < 32; i += 8)
        t[i][tx] = in[(size_t)(r0 + i) * C + c0 + tx];
    __syncthreads();
    for (int i = ty; i < 32; i += 8)
        out[(size_t)(c0 + i) * R + r0 + tx] = (bf16)t[tx][i];
}

// ---------------- per-batch diffusion scale factors ----------------
__global__ void alpha_kernel(const int* __restrict__ tdiff,
                             float* __restrict__ salpha, float* __restrict__ sbeta)
{
    const int b = threadIdx.x;
    const int t = tdiff[b];
    const float step = (0.02f - 1e-4f) / 999.f;
    float prod = 1.f;
    for (int j = 0; j <= t; ++j) prod *= (1.f - (1e-4f + j * step));
    salpha[b] = sqrtf(prod);
    sbeta[b]  = sqrtf(fmaxf(1.f - prod, 0.f));
}

// ---------------- embedding gather-sum from bf16 table ----------------
// 128 threads/block, one (b,s) per block; thread i owns bf16-pair i.
__global__ __launch_bounds__(128) void embed_kernel(
    const int* __restrict__ seqs, const unsigned* __restrict__ emb2,
    float* __restrict__ x, bf16* __restrict__ xb)
{
    __shared__ int idx[Cc];
    const int bs = blockIdx.x;
    const int tid = threadIdx.x;
    if (tid < Cc) idx[tid] = seqs[(size_t)bs * Cc + tid];
    __syncthreads();
    float s0 = 0.f, s1 = 0.f;
#pragma unroll 8
    for (int c = 0; c < Cc; ++c) {
        unsigned u = emb2[(size_t)idx[c] * 128 + tid];
        union { unsigned ui; float f; } lo, hi;
        lo.ui = u << 16;
        hi.ui = u & 0xffff0000u;
        s0 += lo.f;
        s1 += hi.f;
    }
    ((float2*)x)[(size_t)bs * 128 + tid] = make_float2(s0, s1);
    union { bf16 h[2]; unsigned u; } pk;
    pk.h[0] = (bf16)s0; pk.h[1] = (bf16)s1;
    ((unsigned*)xb)[(size_t)bs * 128 + tid] = pk.u;
}

// ---------------- attention: cat build (bf16), logits, apply ----------------
__global__ __launch_bounds__(256) void cat_build_kernel(
    const float* __restrict__ x, const float* __restrict__ w, bf16* __restrict__ cat)
{
    const int r = blockIdx.x;             // b*49+t
    const int b = r / (Ss - 1), t = r % (Ss - 1);
    const int d = threadIdx.x;
    cat[(size_t)r * 512 + d]       = (bf16)x[((size_t)b * Ss) * Dd + d];
    cat[(size_t)r * 512 + 256 + d] = (bf16)w[((size_t)b * Ss + t) * Dd + d];
}

__global__ __launch_bounds__(256) void attn2_kernel(
    const float* __restrict__ H1, const float* __restrict__ W2,
    const float* __restrict__ b2, float* __restrict__ attnw)
{
    const int r = blockIdx.x * 4 + (threadIdx.x >> 6);
    const int j = threadIdx.x & 63;
    float h = H1[(size_t)r * 64 + j];
    float v0 = h * W2[j];
    float v1 = h * W2[64 + j];
#pragma unroll
    for (int off = 32; off; off >>= 1) { v0 += __shfl_down(v0, off); v1 += __shfl_down(v1, off); }
    if (j == 0) {
        float z0 = v0 + b2[0], z1 = v1 + b2[1];
        float m = fmaxf(z0, z1);
        float e0 = expf(z0 - m), e1 = expf(z1 - m);
        float inv = 1.f / (e0 + e1);
        attnw[(size_t)r * 2 + 0] = e0 * inv;
        attnw[(size_t)r * 2 + 1] = e1 * inv;
    }
}

__global__ __launch_bounds__(256) void attn_apply_kernel(
    const float* __restrict__ x, const float* __restrict__ w,
    const float* __restrict__ attnw, float* __restrict__ aligned)
{
    const int bs = blockIdx.x;
    const int b = bs / Ss, s = bs % Ss;
    const int d = threadIdx.x;
    const float ek = x[((size_t)b * Ss) * Dd + d];
    float v;
    if (s == 0) {
        v = ek;
    } else {
        const int r = b * (Ss - 1) + (s - 1);
        const float a0 = attnw[(size_t)r * 2], a1 = attnw[(size_t)r * 2 + 1];
        v = ek * a0 + w[((size_t)b * Ss + s - 1) * Dd + d] * a1;
    }
    aligned[(size_t)bs * Dd + d] = v;
}

// ---------------- diffusion elementwise + noise passthrough ----------------
__global__ __launch_bounds__(256) void diff_kernel(
    const float* __restrict__ aligned, const float* __restrict__ noise,
    const float* __restrict__ temb, const int* __restrict__ tdiff,
    const float* __restrict__ salpha, const float* __restrict__ sbeta,
    bf16* __restrict__ tmpb, float* __restrict__ noise_out)
{
    const int bs = blockIdx.x;
    const int b = bs / Ss;
    const int d = threadIdx.x;
    const size_t i = (size_t)bs * Dd + d;
    const int t = tdiff[b];
    const float nz = noise[i];
    tmpb[i] = (bf16)(aligned[i] * salpha[b] + nz * sbeta[b] + temb[(size_t)t * Dd + d]);
    noise_out[i] = nz;
}

// ---------------- pooled 2-class heads ----------------
__device__ inline void pool_reduce_write(float m, const float* __restrict__ Wout,
                                         const float* __restrict__ bout,
                                         float* __restrict__ outp, int b,
                                         float* r0, float* r1)
{
    float v0 = m * Wout[threadIdx.x];
    float v1 = m * Wout[Dd + threadIdx.x];
#pragma unroll
    for (int off = 32; off; off >>= 1) { v0 += __shfl_down(v0, off); v1 += __shfl_down(v1, off); }
    const int lane = threadIdx.x & 63, wv = threadIdx.x >> 6;
    if (lane == 0) { r0[wv] = v0; r1[wv] = v1; }
    __syncthreads();
    if (threadIdx.x == 0) {
        outp[b * 2 + 0] = r0[0] + r0[1] + r0[2] + r0[3] + bout[0];
        outp[b * 2 + 1] = r1[0] + r1[1] + r1[2] + r1[3] + bout[1];
    }
}

__global__ __launch_bounds__(256) void pool_x_kernel(
    const float* __restrict__ x, const float* __restrict__ Wout,
    const float* __restrict__ bout, float* __restrict__ outp)
{
    __shared__ float r0[4], r1[4];
    const int b = blockIdx.x, d = threadIdx.x;
    float m = -INFINITY;
    for (int s = 0; s < Ss; ++s) m = fmaxf(m, x[((size_t)b * Ss + s) * Dd + d]);
    pool_reduce_write(m, Wout, bout, outp, b, r0, r1);
}

__global__ __launch_bounds__(256) void gen_pool_kernel(
    const float* __restrict__ aligned, const float* __restrict__ noise,
    const float* __restrict__ pred, const float* __restrict__ Wout,
    const float* __restrict__ bout, float* __restrict__ outp)
{
    __shared__ float r0[4], r1[4];
    const int b = blockIdx.x, d = threadIdx.x;
    float m = -INFINITY;
    for (int s = 0; s < Ss; ++s) {
        const size_t i = ((size_t)b * Ss + s) * Dd + d;
        m = fmaxf(m, aligned[i] + noise[i] - pred[i]);
    }
    pool_reduce_write(m, Wout, bout, outp, b, r0, r1);
}

// ---------------- host ----------------
extern "C" void kernel_launch(void* const* d_in, const int* in_sizes, int n_in,
                              void* d_out, int out_size, void* d_ws, size_t ws_size,
                              hipStream_t stream)
{
    const int*   seqs  = (const int*)d_in[0];
    const int*   tdiff = (const int*)d_in[5];
    const float* noise = (const float*)d_in[6];
    const float* emb   = (const float*)d_in[7];
    const float* Wih   = (const float*)d_in[8];
    const float* Whh   = (const float*)d_in[9];
    const float* bih   = (const float*)d_in[10];
    const float* bhh   = (const float*)d_in[11];
    const float* Whk   = (const float*)d_in[12];
    const float* bhk   = (const float*)d_in[13];
    const float* W1    = (const float*)d_in[14];
    const float* b1    = (const float*)d_in[15];
    const float* W2    = (const float*)d_in[16];
    const float* b2    = (const float*)d_in[17];
    const float* Wdiff = (const float*)d_in[18];
    const float* bdiff = (const float*)d_in[19];
    const float* temb  = (const float*)d_in[20];
    const float* Wout  = (const float*)d_in[21];
    const float* bout  = (const float*)d_in[22];

    float* outp = (float*)d_out;
    char*  wsb  = (char*)d_ws;

    float* gates   = (float*)(wsb + OFFB_GATES);
    bf16*  embb    = (bf16*) (wsb + OFFB_EMBB);
    float* aligned = (float*)(wsb + OFFB_ALIGNED);
    bf16*  catb    = (bf16*) (wsb + OFFB_CAT);
    bf16*  tmpb    = (bf16*) (wsb + OFFB_TMPB);
    float* H1      = (float*)(wsb + OFFB_H1);
    float* attnw   = (float*)(wsb + OFFB_ATTNW);
    float* x       = (float*)(wsb + OFFB_X);
    bf16*  xb      = (bf16*) (wsb + OFFB_XB);
    bf16*  rnnb    = (bf16*) (wsb + OFFB_RNNB);
    float* wbuf    = (float*)(wsb + OFFB_W);
    bf16*  Wihb    = (bf16*) (wsb + OFFB_WIHB);
    bf16*  Whhb    = (bf16*) (wsb + OFFB_WHHB);
    bf16*  Whkb    = (bf16*) (wsb + OFFB_WHKB);
    bf16*  W1b     = (bf16*) (wsb + OFFB_W1B);
    bf16*  WdTb    = (bf16*) (wsb + OFFB_WDTB);
    float* salpha  = (float*)(wsb + OFFB_SALPHA);
    float* sbeta   = (float*)(wsb + OFFB_SBETA);
    int*   barcnt  = (int*)  (wsb + OFFB_BAR);

    float* pred_out  = outp + 1024;                        // (B,S,D)
    float* noise_out = outp + 1024 + (size_t)Bb * Ss * Dd; // (B,S,D)

    // barrier counters must start at 0 (ws is poisoned each call)
    hipMemsetAsync(barcnt, 0, 4096, stream);

    alpha_kernel<<<1, 256, 0, stream>>>(tdiff, salpha, sbeta);

    cvt_weights_kernel<<<608, 256, 0, stream>>>(Wih, Whh, Whk, W1,
                                                Wihb, Whhb, Whkb, W1b);
    transpose_cvt_kernel<<<dim3(8, 8), 256, 0, stream>>>(Wdiff, WdTb, 256, 256);
    cvt_emb_kernel<<<5001, 256, 0, stream>>>(emb, embb, 20001 * 64);

    // x = emb[seqs].sum(axis=2)  (fp32 + bf16), bf16 gather
    embed_kernel<<<Bb * Ss, 128, 0, stream>>>(seqs, (const unsigned*)embb, x, xb);

    // pool_x head (only needs x)
    pool_x_kernel<<<Bb, 256, 0, stream>>>(x, Wout, bout, outp);

    // gates_pre = x @ Wih^T + bih + bhh : (12800 x 1024), K=256
    mfma_gemm<128, 128, 0><<<dim3(100, 8), 256, 0, stream>>>(
        xb, 256, Wihb, 256, bih, bhh, gates, 1024, 256);

    // LSTM recurrence: one persistent launch, 50 steps internally
    lstm_persist<<<256, 256, 0, stream>>>(Whhb, gates, rnnb, barcnt);

    // w = rnn @ Whk^T + bhk : (12800 x 256), K=256
    mfma_gemm<128, 128, 0><<<dim3(100, 2), 256, 0, stream>>>(
        rnnb, 256, Whkb, 256, bhk, nullptr, wbuf, 256, 256);

    // attention MLP
    cat_build_kernel<<<Bb * (Ss - 1), 256, 0, stream>>>(x, wbuf, catb);
    mfma_gemm<128, 64, 1><<<dim3(98, 1), 256, 0, stream>>>(
        catb, 512, W1b, 512, b1, nullptr, H1, 64, 512);
    attn2_kernel<<<(Bb * (Ss - 1)) / 4, 256, 0, stream>>>(H1, W2, b2, attnw);
    attn_apply_kernel<<<Bb * Ss, 256, 0, stream>>>(x, wbuf, attnw, aligned);

    // diffusion elementwise (+ noise passthrough fused)
    diff_kernel<<<Bb * Ss, 256, 0, stream>>>(aligned, noise, temb, tdiff,
                                             salpha, sbeta, tmpb, noise_out);

    // predicted_noise = tmp @ Wdiff + bdiff -> d_out
    mfma_gemm<128, 128, 0><<<dim3(100, 2), 256, 0, stream>>>(
        tmpb, 256, WdTb, 256, bdiff, nullptr, pred_out, 256, 256);

    // gen_pool head: max_s(aligned + noise - pred) @ Wout^T + bout
    gen_pool_kernel<<<Bb, 256, 0, stream>>>(aligned, noise, pred_out, Wout, bout, outp + 512);
}

// Round 4
// 750.935 us; speedup vs baseline: 2.3113x; 2.3113x over previous
//
#include <hip/hip_runtime.h>
#include <cmath>

// Problem constants
#define Bb 256
#define Ss 50
#define Cc 40
#define Dd 256
#define Vv 20000

typedef __bf16 bf16;
typedef __bf16 bf16x8 __attribute__((ext_vector_type(8)));
typedef float f32x4 __attribute__((ext_vector_type(4)));

#define GL2LDS(g, l) __builtin_amdgcn_global_load_lds( \
    (__attribute__((address_space(1))) void*)(g), \
    (__attribute__((address_space(3))) void*)(l), 16, 0, 0)

// ---------------- ws layout (BYTE offsets) ----------------
#define OFFB_GATES    0ull
#define OFFB_EMBB     0ull
#define OFFB_ALIGNED  0ull
#define OFFB_CAT      13107200ull
#define OFFB_TMPB     25952256ull
#define OFFB_H1       32505856ull
#define OFFB_ATTNW    35717120ull
#define OFFB_X        52428800ull
#define OFFB_XB       65536000ull
#define OFFB_RNNB     72089600ull
#define OFFB_W        78643200ull
#define OFFB_WIHB     92012544ull
#define OFFB_WHHB     92536832ull
#define OFFB_WHKB     93061120ull
#define OFFB_W1B      93192192ull
#define OFFB_WDTB     93257728ull
#define OFFB_SALPHA   93388800ull
#define OFFB_SBETA    93389824ull

// ---------------- bf16 MFMA GEMM (unchanged) ----------------
template<int BM, int BN, int ACT>
__global__ __launch_bounds__(256) void mfma_gemm(
    const bf16* __restrict__ A, int lda,
    const bf16* __restrict__ B, int ldb,
    const float* __restrict__ bias1, const float* __restrict__ bias2,
    float* __restrict__ C, int ldc, int K)
{
    constexpr int BK = 32;
    constexpr int NF = BN / 32;
    __shared__ bf16 As[BM * BK];
    __shared__ bf16 Bs[BN * BK];
    const int tid  = threadIdx.x;
    const int wave = tid >> 6;
    const int lane = tid & 63;
    const int m0 = blockIdx.x * BM;
    const int n0 = blockIdx.y * BN;
    const int wm = (wave >> 1) * 64;
    const int wn = (wave & 1) * (BN / 2);

    f32x4 acc[4][NF];
#pragma unroll
    for (int i = 0; i < 4; ++i)
#pragma unroll
        for (int j = 0; j < NF; ++j) acc[i][j] = (f32x4){0.f, 0.f, 0.f, 0.f};

    const int ar = tid >> 2;
    const int ac = tid & 3;
    const int sw = ac ^ (ar & 3);
    const int lr = lane & 15;
    const int q  = lane >> 4;

    for (int k0 = 0; k0 < K; k0 += BK) {
        __syncthreads();
#pragma unroll
        for (int it = 0; it < BM / 64; ++it) {
            const bf16* gp = A + (size_t)(m0 + it * 64 + ar) * lda + k0 + sw * 8;
            GL2LDS(gp, As + it * 2048 + wave * 512);
        }
#pragma unroll
        for (int it = 0; it < BN / 64; ++it) {
            const bf16* gp = B + (size_t)(n0 + it * 64 + ar) * ldb + k0 + sw * 8;
            GL2LDS(gp, Bs + it * 2048 + wave * 512);
        }
        __syncthreads();

        bf16x8 af[4], bfv[NF];
#pragma unroll
        for (int fm = 0; fm < 4; ++fm) {
            int m = wm + fm * 16 + lr;
            af[fm] = *(const bf16x8*)(As + m * 32 + ((q ^ (m & 3)) * 8));
        }
#pragma unroll
        for (int fn = 0; fn < NF; ++fn) {
            int n = wn + fn * 16 + lr;
            bfv[fn] = *(const bf16x8*)(Bs + n * 32 + ((q ^ (n & 3)) * 8));
        }
#pragma unroll
        for (int fm = 0; fm < 4; ++fm)
#pragma unroll
            for (int fn = 0; fn < NF; ++fn)
                acc[fm][fn] = __builtin_amdgcn_mfma_f32_16x16x32_bf16(
                    af[fm], bfv[fn], acc[fm][fn], 0, 0, 0);
    }

    const int rbase = q * 4;
#pragma unroll
    for (int fn = 0; fn < NF; ++fn) {
        const int col = n0 + wn + fn * 16 + lr;
        float bb = 0.f;
        if (bias1) bb += bias1[col];
        if (bias2) bb += bias2[col];
#pragma unroll
        for (int fm = 0; fm < 4; ++fm) {
            f32x4 v = acc[fm][fn];
#pragma unroll
            for (int r = 0; r < 4; ++r) {
                const int row = m0 + wm + fm * 16 + rbase + r;
                float val = v[r] + bb;
                if (ACT == 1) val = tanhf(val);
                C[(size_t)row * ldc + col] = val;
            }
        }
    }
}

// ---------------- LSTM recurrence: 16 independent blocks, 1 launch -------
// Block bm owns batches bm*16..+15 and the FULL hidden dim — zero cross-block
// communication (the R3 device-fence-per-step design was a 29us/step L2-flush
// disaster; this keeps all sync intra-CU). 512 threads = 8 waves; wave w owns
// hidden dims w*32..+31 for ALL 4 gates, so the i/f/g/o combine is lane-local
// (MFMA C/D layout: same lane+reg across the 8 acc tiles). h ping-pongs
// through LDS (row pad 264 elems = 528B -> b128 reads ~conflict-free);
// c stays in registers. Whh fragments re-read from L2 each step
// (step-invariant addresses, 512KB/CU/step).
__global__ __launch_bounds__(512, 2) void lstm_rec(
    const bf16* __restrict__ Whhb,    // (1024 x 256) N x K
    const float* __restrict__ gates,  // (B*S x 1024) x@Wih^T+bih+bhh
    bf16* __restrict__ rnnb)          // (B*S x 256) h outputs
{
    __shared__ bf16 hb[2][16][264];
    const int tid  = threadIdx.x;
    const int w    = tid >> 6;
    const int lane = tid & 63;
    const int lr   = lane & 15;
    const int q    = lane >> 4;
    const int bm   = blockIdx.x;
    const int wbase = w * 32;

    // zero h buffer 0 (h_{-1} = 0); uniform loop keeps code simple
    for (int i = tid; i < 16 * 264; i += 512)
        hb[0][i / 264][i % 264] = (bf16)0.f;

    // step-invariant Whh fragment pointers: tile (g,j) row = g*256+wbase+j*16+lr
    const bf16* bptr[4][2];
#pragma unroll
    for (int g = 0; g < 4; ++g)
#pragma unroll
        for (int j = 0; j < 2; ++j)
            bptr[g][j] = Whhb + (size_t)(g * 256 + wbase + j * 16 + lr) * Dd + q * 8;

    // gate-preact row bases: this lane's batch rows are bm*16 + q*4 + r
    const float* gbase[4];
#pragma unroll
    for (int r = 0; r < 4; ++r)
        gbase[r] = gates + (size_t)(bm * 16 + q * 4 + r) * Ss * 1024;

    float c[2][4];
#pragma unroll
    for (int j = 0; j < 2; ++j)
#pragma unroll
        for (int r = 0; r < 4; ++r) c[j][r] = 0.f;

    __syncthreads();

    for (int t = 0; t < Ss; ++t) {
        const int p = t & 1;

        // prefetch gate pre-activations (independent of h)
        float pg[4][2][4];  // [gate][j][reg]
#pragma unroll
        for (int r = 0; r < 4; ++r) {
            const float* gp = gbase[r] + (size_t)t * 1024;
#pragma unroll
            for (int g = 0; g < 4; ++g)
#pragma unroll
                for (int j = 0; j < 2; ++j)
                    pg[g][j][r] = gp[g * 256 + wbase + j * 16 + lr];
        }

        f32x4 acc[4][2];
#pragma unroll
        for (int g = 0; g < 4; ++g)
#pragma unroll
            for (int j = 0; j < 2; ++j) acc[g][j] = (f32x4){0.f, 0.f, 0.f, 0.f};

        // K loop: A from LDS (shared across the 8 tiles), B from L2,
        // double-buffered B fragments
        bf16x8 bcur[4][2], bnxt[4][2];
#pragma unroll
        for (int g = 0; g < 4; ++g)
#pragma unroll
            for (int j = 0; j < 2; ++j) bcur[g][j] = *(const bf16x8*)(bptr[g][j]);

#pragma unroll
        for (int kc = 0; kc < 8; ++kc) {
            bf16x8 a = *(const bf16x8*)&hb[p][lr][kc * 32 + q * 8];
            if (kc < 7) {
#pragma unroll
                for (int g = 0; g < 4; ++g)
#pragma unroll
                    for (int j = 0; j < 2; ++j)
                        bnxt[g][j] = *(const bf16x8*)(bptr[g][j] + (kc + 1) * 32);
            }
#pragma unroll
            for (int g = 0; g < 4; ++g)
#pragma unroll
                for (int j = 0; j < 2; ++j)
                    acc[g][j] = __builtin_amdgcn_mfma_f32_16x16x32_bf16(
                        a, bcur[g][j], acc[g][j], 0, 0, 0);
#pragma unroll
            for (int g = 0; g < 4; ++g)
#pragma unroll
                for (int j = 0; j < 2; ++j) bcur[g][j] = bnxt[g][j];
        }

        // gate math: all 4 gates for (m = q*4+r, d = wbase+j*16+lr) are in
        // this lane at reg r of acc[g][j]
#pragma unroll
        for (int j = 0; j < 2; ++j)
#pragma unroll
            for (int r = 0; r < 4; ++r) {
                float gi = acc[0][j][r] + pg[0][j][r];
                float gf = acc[1][j][r] + pg[1][j][r];
                float gg = acc[2][j][r] + pg[2][j][r];
                float go = acc[3][j][r] + pg[3][j][r];
                float ii = 1.f / (1.f + expf(-gi));
                float ff = 1.f / (1.f + expf(-gf));
                float g2 = tanhf(gg);
                float oo = 1.f / (1.f + expf(-go));
                c[j][r] = ff * c[j][r] + ii * g2;
                float h = oo * tanhf(c[j][r]);
                const int m = q * 4 + r;
                const int d = wbase + j * 16 + lr;
                hb[p ^ 1][m][d] = (bf16)h;
                rnnb[((size_t)(bm * 16 + m) * Ss + t) * Dd + d] = (bf16)h;
            }
        __syncthreads();
    }
}

// ---------------- weight converts (one launch) ----------------
__global__ __launch_bounds__(256) void cvt_weights_kernel(
    const float* __restrict__ Wih, const float* __restrict__ Whh,
    const float* __restrict__ Whk, const float* __restrict__ W1,
    bf16* __restrict__ Wihb, bf16* __restrict__ Whhb,
    bf16* __restrict__ Whkb, bf16* __restrict__ W1b)
{
    int i = blockIdx.x * 256 + threadIdx.x;   // float4 index
    const float* src; bf16* dst; int base;
    if (i < 65536)       { src = Wih; dst = Wihb; base = 0; }
    else if (i < 131072) { src = Whh; dst = Whhb; base = 65536; }
    else if (i < 147456) { src = Whk; dst = Whkb; base = 131072; }
    else                 { src = W1;  dst = W1b;  base = 147456; }
    int j = i - base;
    float4 v = *((const float4*)src + j);
    bf16* o = dst + j * 4;
    o[0] = (bf16)v.x; o[1] = (bf16)v.y; o[2] = (bf16)v.z; o[3] = (bf16)v.w;
}

__global__ __launch_bounds__(256) void cvt_emb_kernel(
    const float* __restrict__ src, bf16* __restrict__ dst, int n4)
{
    int i = blockIdx.x * 256 + threadIdx.x;
    if (i >= n4) return;
    float4 v = *((const float4*)src + i);
    bf16* o = dst + i * 4;
    o[0] = (bf16)v.x; o[1] = (bf16)v.y; o[2] = (bf16)v.z; o[3] = (bf16)v.w;
}

__global__ __launch_bounds__(256) void transpose_cvt_kernel(
    const float* __restrict__ in, bf16* __restrict__ out, int R, int C)
{
    __shared__ float t[32][33];
    const int c0 = blockIdx.x * 32, r0 = blockIdx.y * 32;
    const int tx = threadIdx.x & 31, ty = threadIdx.x >> 5;
    for (int i = ty; i < 32; i += 8)
        t[i][tx] = in[(size_t)(r0 + i) * C + c0 + tx];
    __syncthreads();
    for (int i = ty; i < 32; i += 8)
        out[(size_t)(c0 + i) * R + r0 + tx] = (bf16)t[tx][i];
}

// ---------------- per-batch diffusion scale factors ----------------
__global__ void alpha_kernel(const int* __restrict__ tdiff,
                             float* __restrict__ salpha, float* __restrict__ sbeta)
{
    const int b = threadIdx.x;
    const int t = tdiff[b];
    const float step = (0.02f - 1e-4f) / 999.f;
    float prod = 1.f;
    for (int j = 0; j <= t; ++j) prod *= (1.f - (1e-4f + j * step));
    salpha[b] = sqrtf(prod);
    sbeta[b]  = sqrtf(fmaxf(1.f - prod, 0.f));
}

// ---------------- embedding gather-sum from bf16 table ----------------
__global__ __launch_bounds__(128) void embed_kernel(
    const int* __restrict__ seqs, const unsigned* __restrict__ emb2,
    float* __restrict__ x, bf16* __restrict__ xb)
{
    __shared__ int idx[Cc];
    const int bs = blockIdx.x;
    const int tid = threadIdx.x;
    if (tid < Cc) idx[tid] = seqs[(size_t)bs * Cc + tid];
    __syncthreads();
    float s0 = 0.f, s1 = 0.f;
#pragma unroll 8
    for (int c = 0; c < Cc; ++c) {
        unsigned u = emb2[(size_t)idx[c] * 128 + tid];
        union { unsigned ui; float f; } lo, hi;
        lo.ui = u << 16;
        hi.ui = u & 0xffff0000u;
        s0 += lo.f;
        s1 += hi.f;
    }
    ((float2*)x)[(size_t)bs * 128 + tid] = make_float2(s0, s1);
    union { bf16 h[2]; unsigned u; } pk;
    pk.h[0] = (bf16)s0; pk.h[1] = (bf16)s1;
    ((unsigned*)xb)[(size_t)bs * 128 + tid] = pk.u;
}

// ---------------- attention: cat build (bf16), logits, apply ----------------
__global__ __launch_bounds__(256) void cat_build_kernel(
    const float* __restrict__ x, const float* __restrict__ w, bf16* __restrict__ cat)
{
    const int r = blockIdx.x;             // b*49+t
    const int b = r / (Ss - 1), t = r % (Ss - 1);
    const int d = threadIdx.x;
    cat[(size_t)r * 512 + d]       = (bf16)x[((size_t)b * Ss) * Dd + d];
    cat[(size_t)r * 512 + 256 + d] = (bf16)w[((size_t)b * Ss + t) * Dd + d];
}

__global__ __launch_bounds__(256) void attn2_kernel(
    const float* __restrict__ H1, const float* __restrict__ W2,
    const float* __restrict__ b2, float* __restrict__ attnw)
{
    const int r = blockIdx.x * 4 + (threadIdx.x >> 6);
    const int j = threadIdx.x & 63;
    float h = H1[(size_t)r * 64 + j];
    float v0 = h * W2[j];
    float v1 = h * W2[64 + j];
#pragma unroll
    for (int off = 32; off; off >>= 1) { v0 += __shfl_down(v0, off); v1 += __shfl_down(v1, off); }
    if (j == 0) {
        float z0 = v0 + b2[0], z1 = v1 + b2[1];
        float m = fmaxf(z0, z1);
        float e0 = expf(z0 - m), e1 = expf(z1 - m);
        float inv = 1.f / (e0 + e1);
        attnw[(size_t)r * 2 + 0] = e0 * inv;
        attnw[(size_t)r * 2 + 1] = e1 * inv;
    }
}

__global__ __launch_bounds__(256) void attn_apply_kernel(
    const float* __restrict__ x, const float* __restrict__ w,
    const float* __restrict__ attnw, float* __restrict__ aligned)
{
    const int bs = blockIdx.x;
    const int b = bs / Ss, s = bs % Ss;
    const int d = threadIdx.x;
    const float ek = x[((size_t)b * Ss) * Dd + d];
    float v;
    if (s == 0) {
        v = ek;
    } else {
        const int r = b * (Ss - 1) + (s - 1);
        const float a0 = attnw[(size_t)r * 2], a1 = attnw[(size_t)r * 2 + 1];
        v = ek * a0 + w[((size_t)b * Ss + s - 1) * Dd + d] * a1;
    }
    aligned[(size_t)bs * Dd + d] = v;
}

// ---------------- diffusion elementwise + noise passthrough ----------------
__global__ __launch_bounds__(256) void diff_kernel(
    const float* __restrict__ aligned, const float* __restrict__ noise,
    const float* __restrict__ temb, const int* __restrict__ tdiff,
    const float* __restrict__ salpha, const float* __restrict__ sbeta,
    bf16* __restrict__ tmpb, float* __restrict__ noise_out)
{
    const int bs = blockIdx.x;
    const int b = bs / Ss;
    const int d = threadIdx.x;
    const size_t i = (size_t)bs * Dd + d;
    const int t = tdiff[b];
    const float nz = noise[i];
    tmpb[i] = (bf16)(aligned[i] * salpha[b] + nz * sbeta[b] + temb[(size_t)t * Dd + d]);
    noise_out[i] = nz;
}

// ---------------- pooled 2-class heads ----------------
__device__ inline void pool_reduce_write(float m, const float* __restrict__ Wout,
                                         const float* __restrict__ bout,
                                         float* __restrict__ outp, int b,
                                         float* r0, float* r1)
{
    float v0 = m * Wout[threadIdx.x];
    float v1 = m * Wout[Dd + threadIdx.x];
#pragma unroll
    for (int off = 32; off; off >>= 1) { v0 += __shfl_down(v0, off); v1 += __shfl_down(v1, off); }
    const int lane = threadIdx.x & 63, wv = threadIdx.x >> 6;
    if (lane == 0) { r0[wv] = v0; r1[wv] = v1; }
    __syncthreads();
    if (threadIdx.x == 0) {
        outp[b * 2 + 0] = r0[0] + r0[1] + r0[2] + r0[3] + bout[0];
        outp[b * 2 + 1] = r1[0] + r1[1] + r1[2] + r1[3] + bout[1];
    }
}

__global__ __launch_bounds__(256) void pool_x_kernel(
    const float* __restrict__ x, const float* __restrict__ Wout,
    const float* __restrict__ bout, float* __restrict__ outp)
{
    __shared__ float r0[4], r1[4];
    const int b = blockIdx.x, d = threadIdx.x;
    float m = -INFINITY;
    for (int s = 0; s < Ss; ++s) m = fmaxf(m, x[((size_t)b * Ss + s) * Dd + d]);
    pool_reduce_write(m, Wout, bout, outp, b, r0, r1);
}

__global__ __launch_bounds__(256) void gen_pool_kernel(
    const float* __restrict__ aligned, const float* __restrict__ noise,
    const float* __restrict__ pred, const float* __restrict__ Wout,
    const float* __restrict__ bout, float* __restrict__ outp)
{
    __shared__ float r0[4], r1[4];
    const int b = blockIdx.x, d = threadIdx.x;
    float m = -INFINITY;
    for (int s = 0; s < Ss; ++s) {
        const size_t i = ((size_t)b * Ss + s) * Dd + d;
        m = fmaxf(m, aligned[i] + noise[i] - pred[i]);
    }
    pool_reduce_write(m, Wout, bout, outp, b, r0, r1);
}

// ---------------- host ----------------
extern "C" void kernel_launch(void* const* d_in, const int* in_sizes, int n_in,
                              void* d_out, int out_size, void* d_ws, size_t ws_size,
                              hipStream_t stream)
{
    const int*   seqs  = (const int*)d_in[0];
    const int*   tdiff = (const int*)d_in[5];
    const float* noise = (const float*)d_in[6];
    const float* emb   = (const float*)d_in[7];
    const float* Wih   = (const float*)d_in[8];
    const float* Whh   = (const float*)d_in[9];
    const float* bih   = (const float*)d_in[10];
    const float* bhh   = (const float*)d_in[11];
    const float* Whk   = (const float*)d_in[12];
    const float* bhk   = (const float*)d_in[13];
    const float* W1    = (const float*)d_in[14];
    const float* b1    = (const float*)d_in[15];
    const float* W2    = (const float*)d_in[16];
    const float* b2    = (const float*)d_in[17];
    const float* Wdiff = (const float*)d_in[18];
    const float* bdiff = (const float*)d_in[19];
    const float* temb  = (const float*)d_in[20];
    const float* Wout  = (const float*)d_in[21];
    const float* bout  = (const float*)d_in[22];

    float* outp = (float*)d_out;
    char*  wsb  = (char*)d_ws;

    float* gates   = (float*)(wsb + OFFB_GATES);
    bf16*  embb    = (bf16*) (wsb + OFFB_EMBB);
    float* aligned = (float*)(wsb + OFFB_ALIGNED);
    bf16*  catb    = (bf16*) (wsb + OFFB_CAT);
    bf16*  tmpb    = (bf16*) (wsb + OFFB_TMPB);
    float* H1      = (float*)(wsb + OFFB_H1);
    float* attnw   = (float*)(wsb + OFFB_ATTNW);
    float* x       = (float*)(wsb + OFFB_X);
    bf16*  xb      = (bf16*) (wsb + OFFB_XB);
    bf16*  rnnb    = (bf16*) (wsb + OFFB_RNNB);
    float* wbuf    = (float*)(wsb + OFFB_W);
    bf16*  Wihb    = (bf16*) (wsb + OFFB_WIHB);
    bf16*  Whhb    = (bf16*) (wsb + OFFB_WHHB);
    bf16*  Whkb    = (bf16*) (wsb + OFFB_WHKB);
    bf16*  W1b     = (bf16*) (wsb + OFFB_W1B);
    bf16*  WdTb    = (bf16*) (wsb + OFFB_WDTB);
    float* salpha  = (float*)(wsb + OFFB_SALPHA);
    float* sbeta   = (float*)(wsb + OFFB_SBETA);

    float* pred_out  = outp + 1024;                        // (B,S,D)
    float* noise_out = outp + 1024 + (size_t)Bb * Ss * Dd; // (B,S,D)

    alpha_kernel<<<1, 256, 0, stream>>>(tdiff, salpha, sbeta);

    cvt_weights_kernel<<<608, 256, 0, stream>>>(Wih, Whh, Whk, W1,
                                                Wihb, Whhb, Whkb, W1b);
    transpose_cvt_kernel<<<dim3(8, 8), 256, 0, stream>>>(Wdiff, WdTb, 256, 256);
    cvt_emb_kernel<<<5001, 256, 0, stream>>>(emb, embb, 20001 * 64);

    // x = emb[seqs].sum(axis=2)  (fp32 + bf16), bf16 gather
    embed_kernel<<<Bb * Ss, 128, 0, stream>>>(seqs, (const unsigned*)embb, x, xb);

    // pool_x head (only needs x)
    pool_x_kernel<<<Bb, 256, 0, stream>>>(x, Wout, bout, outp);

    // gates_pre = x @ Wih^T + bih + bhh : (12800 x 1024), K=256
    mfma_gemm<128, 128, 0><<<dim3(100, 8), 256, 0, stream>>>(
        xb, 256, Wihb, 256, bih, bhh, gates, 1024, 256);

    // LSTM recurrence: one launch, 16 independent blocks, no global sync
    lstm_rec<<<16, 512, 0, stream>>>(Whhb, gates, rnnb);

    // w = rnn @ Whk^T + bhk : (12800 x 256), K=256
    mfma_gemm<128, 128, 0><<<dim3(100, 2), 256, 0, stream>>>(
        rnnb, 256, Whkb, 256, bhk, nullptr, wbuf, 256, 256);

    // attention MLP
    cat_build_kernel<<<Bb * (Ss - 1), 256, 0, stream>>>(x, wbuf, catb);
    mfma_gemm<128, 64, 1><<<dim3(98, 1), 256, 0, stream>>>(
        catb, 512, W1b, 512, b1, nullptr, H1, 64, 512);
    attn2_kernel<<<(Bb * (Ss - 1)) / 4, 256, 0, stream>>>(H1, W2, b2, attnw);
    attn_apply_kernel<<<Bb * Ss, 256, 0, stream>>>(x, wbuf, attnw, aligned);

    // diffusion elementwise (+ noise passthrough fused)
    diff_kernel<<<Bb * Ss, 256, 0, stream>>>(aligned, noise, temb, tdiff,
                                             salpha, sbeta, tmpb, noise_out);

    // predicted_noise = tmp @ Wdiff + bdiff -> d_out
    mfma_gemm<128, 128, 0><<<dim3(100, 2), 256, 0, stream>>>(
        tmpb, 256, WdTb, 256, bdiff, nullptr, pred_out, 256, 256);

    // gen_pool head: max_s(aligned + noise - pred) @ Wout^T + bout
    gen_pool_kernel<<<Bb, 256, 0, stream>>>(aligned, noise, pred_out, Wout, bout, outp + 512);
}